// Round 2
// baseline (518.595 us; speedup 1.0000x reference)
//
#include <hip/hip_runtime.h>
#include <hip/hip_bf16.h>

// Sizes fixed by the reference
#define B_ 16
#define H_ 2048
#define W_ 128

using f32x4  = __attribute__((ext_vector_type(4))) float;
using bf16x8 = __attribute__((ext_vector_type(8))) short;

// ---------------------------------------------------------------------------
// K0a: per-row sums s[b,h] = sum_w x, plus bf16 copy Xb[b][h][w]
// one wave per row, 4 rows per block
// ---------------------------------------------------------------------------
__global__ __launch_bounds__(256) void prep_rows(const float* __restrict__ x,
                                                 __hip_bfloat16* __restrict__ Xb,
                                                 float* __restrict__ s) {
    int wave = threadIdx.x >> 6;
    int lane = threadIdx.x & 63;
    int row  = blockIdx.x * 4 + wave;                  // 0 .. B_*H_-1
    const float2 v = *reinterpret_cast<const float2*>(x + (size_t)row * W_ + lane * 2);
    __hip_bfloat162 h2;
    h2.x = __float2bfloat16(v.x);
    h2.y = __float2bfloat16(v.y);
    *reinterpret_cast<__hip_bfloat162*>(Xb + (size_t)row * W_ + lane * 2) = h2;
    float sum = v.x + v.y;
#pragma unroll
    for (int m = 1; m < 64; m <<= 1) sum += __shfl_xor(sum, m, 64);
    if (lane == 0) s[row] = sum;
}

// ---------------------------------------------------------------------------
// K0b: XT[b][w][h] = bf16(x[b][h][w])  (64x64 LDS tile transpose)
// ---------------------------------------------------------------------------
__global__ __launch_bounds__(256) void prep_xt(const float* __restrict__ x,
                                               __hip_bfloat16* __restrict__ XT) {
    __shared__ float tile[64][65];
    int bid = blockIdx.x;
    int wb = bid & 1;
    int hb = (bid >> 1) & 31;
    int b  = bid >> 6;
    int h0 = hb * 64, w0 = wb * 64;
    const float* xb = x + (size_t)b * H_ * W_;
    int tx = threadIdx.x & 63, ty = threadIdx.x >> 6;
#pragma unroll
    for (int p = 0; p < 16; ++p) {
        int hl = p * 4 + ty;
        tile[hl][tx] = xb[(size_t)(h0 + hl) * W_ + w0 + tx];
    }
    __syncthreads();
    __hip_bfloat16* xt = XT + (size_t)b * W_ * H_;
#pragma unroll
    for (int p = 0; p < 16; ++p) {
        int wl = p * 4 + ty;
        xt[(size_t)(w0 + wl) * H_ + h0 + tx] = __float2bfloat16(tile[tx][wl]);
    }
}

// ---------------------------------------------------------------------------
// K1: per-row min/max of t[b,h,g] = A*S_hg + C*s_g, S = X X^T via bf16 MFMA.
// grid = B_*H_/16 blocks; block = 16 h-rows; 4 waves each own a 512-wide
// g-slice; block-level min/max reduce via LDS.
// ---------------------------------------------------------------------------
__global__ __launch_bounds__(256, 4) void pass1_stats(
    const __hip_bfloat16* __restrict__ Xb, const float* __restrict__ s,
    const float* __restrict__ w1, const float* __restrict__ b1,
    const float* __restrict__ w2, const float* __restrict__ b2,
    float* __restrict__ mn_out, float* __restrict__ mx_out) {
    __shared__ float red_mn[4][16];
    __shared__ float red_mx[4][16];

    float A = 0.f, C = 0.f;
#pragma unroll
    for (int c = 0; c < 8; ++c) { A += w1[c] * w2[c]; C += b1[c] * w2[c]; }

    int wave = threadIdx.x >> 6, lane = threadIdx.x & 63;
    int q = lane >> 4, r = lane & 15;
    int b = blockIdx.x >> 7, hb = blockIdx.x & 127;
    int h0 = hb * 16;

    const __hip_bfloat16* xb = Xb + (size_t)b * H_ * W_;
    const float* sb = s + b * H_;

    bf16x8 afr[4];
#pragma unroll
    for (int k = 0; k < 4; ++k)
        afr[k] = *reinterpret_cast<const bf16x8*>(xb + (size_t)(h0 + r) * W_ + k * 32 + q * 8);

    float mnv[4], mxv[4];
#pragma unroll
    for (int i = 0; i < 4; ++i) { mnv[i] = 3.4e38f; mxv[i] = -3.4e38f; }

    int gbeg = wave * (H_ / 4), gend = gbeg + (H_ / 4);
    for (int g0 = gbeg; g0 < gend; g0 += 16) {
        f32x4 acc = {0.f, 0.f, 0.f, 0.f};
#pragma unroll
        for (int k = 0; k < 4; ++k) {
            bf16x8 bfr = *reinterpret_cast<const bf16x8*>(xb + (size_t)(g0 + r) * W_ + k * 32 + q * 8);
            acc = __builtin_amdgcn_mfma_f32_16x16x32_bf16(afr[k], bfr, acc, 0, 0, 0);
        }
        float sg = sb[g0 + r];
#pragma unroll
        for (int reg = 0; reg < 4; ++reg) {
            float t = A * acc[reg] + C * sg;   // D frag: col(g)=lane&15, row(h)=q*4+reg
            mnv[reg] = fminf(mnv[reg], t);
            mxv[reg] = fmaxf(mxv[reg], t);
        }
    }
#pragma unroll
    for (int reg = 0; reg < 4; ++reg) {
#pragma unroll
        for (int m = 1; m < 16; m <<= 1) {
            mnv[reg] = fminf(mnv[reg], __shfl_xor(mnv[reg], m, 64));
            mxv[reg] = fmaxf(mxv[reg], __shfl_xor(mxv[reg], m, 64));
        }
        if (r == 0) {
            red_mn[wave][q * 4 + reg] = mnv[reg];
            red_mx[wave][q * 4 + reg] = mxv[reg];
        }
    }
    __syncthreads();
    if (threadIdx.x < 16) {
        int h = threadIdx.x;
        float mn = fminf(fminf(red_mn[0][h], red_mn[1][h]), fminf(red_mn[2][h], red_mn[3][h]));
        float mx = fmaxf(fmaxf(red_mx[0][h], red_mx[1][h]), fmaxf(red_mx[2][h], red_mx[3][h]));
        mn_out[b * H_ + h0 + h] = mn;
        mx_out[b * H_ + h0 + h] = mx;
    }
}

// ---------------------------------------------------------------------------
// K2: recompute S tile, e = exp2((t-mn)*inv), Z = sum e, O = P @ X via MFMA.
// Block = 16 h-rows, 4 waves each own a 512-wide g-slice. O combined via LDS
// f32 atomicAdd tile; Z via small LDS reduce. out = gamma*O/Z + x.
// ---------------------------------------------------------------------------
__global__ __launch_bounds__(256, 4) void pass2_out(
    const float* __restrict__ x,
    const __hip_bfloat16* __restrict__ Xb, const __hip_bfloat16* __restrict__ XT,
    const float* __restrict__ s,
    const float* __restrict__ mn_in, const float* __restrict__ mx_in,
    const float* __restrict__ w1, const float* __restrict__ b1,
    const float* __restrict__ w2, const float* __restrict__ b2,
    const float* __restrict__ gamma, float* __restrict__ out) {
    __shared__ float oacc[16 * 128];                  // 8 KB accumulation tile
    __shared__ __hip_bfloat16 pbuf[4][512];           // per-wave 16h x 32g (swizzled)
    __shared__ float zred[4][16];
    __shared__ float zfin[16];

    float A = 0.f, C = 0.f;
#pragma unroll
    for (int c = 0; c < 8; ++c) { A += w1[c] * w2[c]; C += b1[c] * w2[c]; }

    int wave = threadIdx.x >> 6, lane = threadIdx.x & 63;
    int q = lane >> 4, r = lane & 15;
    int b = blockIdx.x >> 7, hb = blockIdx.x & 127;
    int h0 = hb * 16;

    // zero the accumulation tile before any atomics
    for (int i = threadIdx.x; i < 16 * 128; i += 256) oacc[i] = 0.f;

    const __hip_bfloat16* xb = Xb + (size_t)b * H_ * W_;
    const __hip_bfloat16* xt = XT + (size_t)b * W_ * H_;
    const float* sb = s + b * H_;

    bf16x8 afr[4];
#pragma unroll
    for (int k = 0; k < 4; ++k)
        afr[k] = *reinterpret_cast<const bf16x8*>(xb + (size_t)(h0 + r) * W_ + k * 32 + q * 8);

    const float LOG2E = 1.4426950408889634f;
    float c1[4], c0[4];
#pragma unroll
    for (int reg = 0; reg < 4; ++reg) {
        int h = h0 + q * 4 + reg;
        float mn = mn_in[b * H_ + h], mx = mx_in[b * H_ + h];
        float inv = LOG2E / (mx - mn + 1e-8f);
        c1[reg] = inv;
        c0[reg] = -mn * inv;
    }

    f32x4 o[8];
#pragma unroll
    for (int i = 0; i < 8; ++i) o[i] = (f32x4){0.f, 0.f, 0.f, 0.f};
    float zacc[4] = {0.f, 0.f, 0.f, 0.f};

    __hip_bfloat16* pw = pbuf[wave];
    __syncthreads();   // oacc zeroed

    int gbeg = wave * (H_ / 4), gend = gbeg + (H_ / 4);
    for (int g0 = gbeg; g0 < gend; g0 += 32) {
        // S phase: two 16-g sub-tiles
        f32x4 sacc0 = {0.f, 0.f, 0.f, 0.f}, sacc1 = {0.f, 0.f, 0.f, 0.f};
#pragma unroll
        for (int k = 0; k < 4; ++k) {
            bf16x8 bfr = *reinterpret_cast<const bf16x8*>(xb + (size_t)(g0 + r) * W_ + k * 32 + q * 8);
            sacc0 = __builtin_amdgcn_mfma_f32_16x16x32_bf16(afr[k], bfr, sacc0, 0, 0, 0);
        }
#pragma unroll
        for (int k = 0; k < 4; ++k) {
            bf16x8 bfr = *reinterpret_cast<const bf16x8*>(xb + (size_t)(g0 + 16 + r) * W_ + k * 32 + q * 8);
            sacc1 = __builtin_amdgcn_mfma_f32_16x16x32_bf16(afr[k], bfr, sacc1, 0, 0, 0);
        }
        // issue B-operand loads for GEMM2 early: latency hides under exp+LDS
        bf16x8 btf[8];
#pragma unroll
        for (int nt2 = 0; nt2 < 8; ++nt2)
            btf[nt2] = *reinterpret_cast<const bf16x8*>(xt + (size_t)(nt2 * 16 + r) * H_ + g0 + q * 8);

        float sg0 = sb[g0 + r], sg1 = sb[g0 + 16 + r];
#pragma unroll
        for (int reg = 0; reg < 4; ++reg) {
            int h = q * 4 + reg;
            {
                float t = A * sacc0[reg] + C * sg0;
                float e = exp2f(fmaf(t, c1[reg], c0[reg]));
                zacc[reg] += e;
                int g = r;
                int cc = (g >> 3) ^ ((h >> 1) & 3);
                pw[h * 32 + cc * 8 + (g & 7)] = __float2bfloat16(e);
            }
            {
                float t = A * sacc1[reg] + C * sg1;
                float e = exp2f(fmaf(t, c1[reg], c0[reg]));
                zacc[reg] += e;
                int g = 16 + r;
                int cc = (g >> 3) ^ ((h >> 1) & 3);
                pw[h * 32 + cc * 8 + (g & 7)] = __float2bfloat16(e);
            }
        }
        // A-operand of GEMM2 from LDS
        int cA = q ^ ((r >> 1) & 3);
        bf16x8 pa = *reinterpret_cast<const bf16x8*>(
            reinterpret_cast<const char*>(pw) + r * 64 + cA * 16);
#pragma unroll
        for (int nt2 = 0; nt2 < 8; ++nt2)
            o[nt2] = __builtin_amdgcn_mfma_f32_16x16x32_bf16(pa, btf[nt2], o[nt2], 0, 0, 0);
    }

    // Z: reduce across the 16 r-lanes sharing each h-row, then across waves
#pragma unroll
    for (int reg = 0; reg < 4; ++reg) {
#pragma unroll
        for (int m = 1; m < 16; m <<= 1) zacc[reg] += __shfl_xor(zacc[reg], m, 64);
        if (r == 0) zred[wave][q * 4 + reg] = zacc[reg];
    }
    // O: combine wave partials into the LDS tile
#pragma unroll
    for (int nt2 = 0; nt2 < 8; ++nt2) {
#pragma unroll
        for (int reg = 0; reg < 4; ++reg)
            atomicAdd(&oacc[(q * 4 + reg) * 128 + nt2 * 16 + r], o[nt2][reg]);
    }
    __syncthreads();
    if (threadIdx.x < 16) {
        float z = zred[0][threadIdx.x] + zred[1][threadIdx.x] +
                  zred[2][threadIdx.x] + zred[3][threadIdx.x];
        zfin[threadIdx.x] = gamma[0] / z;
    }
    __syncthreads();

    const float* xrow = x + ((size_t)b * H_ + h0) * W_;
    float* orow = out + ((size_t)b * H_ + h0) * W_;
    for (int i = threadIdx.x * 4; i < 16 * 128; i += 256 * 4) {
        int h = i >> 7;
        float sc = zfin[h];
        float4 xv = *reinterpret_cast<const float4*>(xrow + i);
        float4 ov = *reinterpret_cast<const float4*>(&oacc[i]);
        float4 res;
        res.x = fmaf(sc, ov.x, xv.x);
        res.y = fmaf(sc, ov.y, xv.y);
        res.z = fmaf(sc, ov.z, xv.z);
        res.w = fmaf(sc, ov.w, xv.w);
        *reinterpret_cast<float4*>(orow + i) = res;
    }
}

// ---------------------------------------------------------------------------
extern "C" void kernel_launch(void* const* d_in, const int* in_sizes, int n_in,
                              void* d_out, int out_size, void* d_ws, size_t ws_size,
                              hipStream_t stream) {
    const float* x     = (const float*)d_in[0];
    const float* w1    = (const float*)d_in[1];
    const float* b1    = (const float*)d_in[2];
    const float* w2    = (const float*)d_in[3];
    const float* b2    = (const float*)d_in[4];
    const float* gamma = (const float*)d_in[5];
    float* out = (float*)d_out;

    char* ws = (char*)d_ws;
    const size_t XB_BYTES = (size_t)B_ * H_ * W_ * 2;   // 8 MB
    __hip_bfloat16* Xb = (__hip_bfloat16*)ws;
    __hip_bfloat16* XT = (__hip_bfloat16*)(ws + XB_BYTES);
    float* s  = (float*)(ws + 2 * XB_BYTES);
    float* mn = (float*)(ws + 2 * XB_BYTES + (size_t)B_ * H_ * 4);
    float* mx = (float*)(ws + 2 * XB_BYTES + (size_t)2 * B_ * H_ * 4);

    prep_rows<<<B_ * H_ / 4, 256, 0, stream>>>(x, Xb, s);
    prep_xt<<<B_ * 32 * 2, 256, 0, stream>>>(x, XT);
    pass1_stats<<<B_ * H_ / 16, 256, 0, stream>>>(Xb, s, w1, b1, w2, b2, mn, mx);
    pass2_out<<<B_ * H_ / 16, 256, 0, stream>>>(x, Xb, XT, s, mn, mx, w1, b1, w2, b2, gamma, out);
}

// Round 3
// 464.299 us; speedup vs baseline: 1.1169x; 1.1169x over previous
//
#include <hip/hip_runtime.h>
#include <hip/hip_bf16.h>

// Sizes fixed by the reference
#define B_ 16
#define H_ 2048
#define W_ 128

using f32x4  = __attribute__((ext_vector_type(4))) float;
using bf16x8 = __attribute__((ext_vector_type(8))) short;

// ---------------------------------------------------------------------------
// K0a: per-row sums s[b,h] = sum_w x, plus bf16 copy Xb[b][h][w]
// ---------------------------------------------------------------------------
__global__ __launch_bounds__(256) void prep_rows(const float* __restrict__ x,
                                                 __hip_bfloat16* __restrict__ Xb,
                                                 float* __restrict__ s) {
    int wave = threadIdx.x >> 6;
    int lane = threadIdx.x & 63;
    int row  = blockIdx.x * 4 + wave;                  // 0 .. B_*H_-1
    const float2 v = *reinterpret_cast<const float2*>(x + (size_t)row * W_ + lane * 2);
    __hip_bfloat162 h2;
    h2.x = __float2bfloat16(v.x);
    h2.y = __float2bfloat16(v.y);
    *reinterpret_cast<__hip_bfloat162*>(Xb + (size_t)row * W_ + lane * 2) = h2;
    float sum = v.x + v.y;
#pragma unroll
    for (int m = 1; m < 64; m <<= 1) sum += __shfl_xor(sum, m, 64);
    if (lane == 0) s[row] = sum;
}

// ---------------------------------------------------------------------------
// K0b: XT[b][w][h] = bf16(x[b][h][w])  (64x64 LDS tile transpose)
// ---------------------------------------------------------------------------
__global__ __launch_bounds__(256) void prep_xt(const float* __restrict__ x,
                                               __hip_bfloat16* __restrict__ XT) {
    __shared__ float tile[64][65];
    int bid = blockIdx.x;
    int wb = bid & 1;
    int hb = (bid >> 1) & 31;
    int b  = bid >> 6;
    int h0 = hb * 64, w0 = wb * 64;
    const float* xb = x + (size_t)b * H_ * W_;
    int tx = threadIdx.x & 63, ty = threadIdx.x >> 6;
#pragma unroll
    for (int p = 0; p < 16; ++p) {
        int hl = p * 4 + ty;
        tile[hl][tx] = xb[(size_t)(h0 + hl) * W_ + w0 + tx];
    }
    __syncthreads();
    __hip_bfloat16* xt = XT + (size_t)b * W_ * H_;
#pragma unroll
    for (int p = 0; p < 16; ++p) {
        int wl = p * 4 + ty;
        xt[(size_t)(w0 + wl) * H_ + h0 + tx] = __float2bfloat16(tile[tx][wl]);
    }
}

// ---------------------------------------------------------------------------
// Fused kernel: block = 64 h-rows (4 waves x 16 rows), wave keeps its
// 16x128 A-fragment in registers across both sweeps.
//  sweep1: min/max of t[h,g] = A*S_hg + C*s_g over all g  (stats per-wave)
//  sweep2: e = exp2((t-mn)*inv), Z += e, O += P @ X  (P via per-wave
//          double-buffered swizzled LDS; B-op of PV from XT, prefetchable)
//  epilogue: out = gamma*O/Z + x
// grid = B_ * H_/64 = 512 blocks, XCD-swizzled (64 consecutive per XCD).
// ---------------------------------------------------------------------------
__global__ __launch_bounds__(256, 2) void fused_attn(
    const float* __restrict__ x,
    const __hip_bfloat16* __restrict__ Xb, const __hip_bfloat16* __restrict__ XT,
    const float* __restrict__ s,
    const float* __restrict__ w1, const float* __restrict__ b1,
    const float* __restrict__ w2, const float* __restrict__ b2,
    const float* __restrict__ gamma, float* __restrict__ out) {
    __shared__ __hip_bfloat16 pbuf[4][2][512];   // per-wave 16h x 32g, dbuf

    float A = 0.f, C = 0.f;
#pragma unroll
    for (int c = 0; c < 8; ++c) { A += w1[c] * w2[c]; C += b1[c] * w2[c]; }

    int wave = threadIdx.x >> 6, lane = threadIdx.x & 63;
    int q = lane >> 4, r = lane & 15;

    // XCD swizzle: 512 blocks, XCD k gets a contiguous 64-block span = 2 batches
    int bid = blockIdx.x;
    int swz = (bid & 7) * 64 + (bid >> 3);
    int b  = swz >> 5;
    int hb = swz & 31;
    int h0 = hb * 64 + wave * 16;                // wave's 16 h-rows

    const __hip_bfloat16* xb = Xb + (size_t)b * H_ * W_;
    const __hip_bfloat16* xt = XT + (size_t)b * W_ * H_;
    const float* sb = s + b * H_;

    // A-fragment: 16h x 128k, lives in regs for the whole kernel
    bf16x8 afr[4];
#pragma unroll
    for (int k = 0; k < 4; ++k)
        afr[k] = *reinterpret_cast<const bf16x8*>(xb + (size_t)(h0 + r) * W_ + k * 32 + q * 8);

    // ---------------- sweep 1: per-row min / max ----------------
    float mnv[4], mxv[4];
#pragma unroll
    for (int i = 0; i < 4; ++i) { mnv[i] = 3.4e38f; mxv[i] = -3.4e38f; }

    for (int g0 = 0; g0 < H_; g0 += 32) {
        bf16x8 bfr0[4], bfr1[4];
#pragma unroll
        for (int k = 0; k < 4; ++k) {
            bfr0[k] = *reinterpret_cast<const bf16x8*>(xb + (size_t)(g0 + r) * W_ + k * 32 + q * 8);
            bfr1[k] = *reinterpret_cast<const bf16x8*>(xb + (size_t)(g0 + 16 + r) * W_ + k * 32 + q * 8);
        }
        f32x4 sacc0 = {0.f, 0.f, 0.f, 0.f}, sacc1 = {0.f, 0.f, 0.f, 0.f};
#pragma unroll
        for (int k = 0; k < 4; ++k) {
            sacc0 = __builtin_amdgcn_mfma_f32_16x16x32_bf16(afr[k], bfr0[k], sacc0, 0, 0, 0);
            sacc1 = __builtin_amdgcn_mfma_f32_16x16x32_bf16(afr[k], bfr1[k], sacc1, 0, 0, 0);
        }
        float sg0 = sb[g0 + r], sg1 = sb[g0 + 16 + r];
#pragma unroll
        for (int reg = 0; reg < 4; ++reg) {
            float t0 = A * sacc0[reg] + C * sg0;
            float t1 = A * sacc1[reg] + C * sg1;
            mnv[reg] = fminf(mnv[reg], fminf(t0, t1));
            mxv[reg] = fmaxf(mxv[reg], fmaxf(t0, t1));
        }
    }
    // reduce over the 16 r-lanes sharing each h-row; every lane gets result
#pragma unroll
    for (int reg = 0; reg < 4; ++reg) {
#pragma unroll
        for (int m = 1; m < 16; m <<= 1) {
            mnv[reg] = fminf(mnv[reg], __shfl_xor(mnv[reg], m, 64));
            mxv[reg] = fmaxf(mxv[reg], __shfl_xor(mxv[reg], m, 64));
        }
    }
    const float LOG2E = 1.4426950408889634f;
    float c1[4], c0[4];
#pragma unroll
    for (int reg = 0; reg < 4; ++reg) {
        float inv = LOG2E / (mxv[reg] - mnv[reg] + 1e-8f);
        c1[reg] = inv;
        c0[reg] = -mnv[reg] * inv;
    }

    // ---------------- sweep 2: exp + Z + O = P @ X ----------------
    f32x4 o[8];
#pragma unroll
    for (int i = 0; i < 8; ++i) o[i] = (f32x4){0.f, 0.f, 0.f, 0.f};
    float zacc[4] = {0.f, 0.f, 0.f, 0.f};

    for (int g0 = 0; g0 < H_; g0 += 32) {
        __hip_bfloat16* pw = pbuf[wave][(g0 >> 5) & 1];
        // loads first (prefetchable): S B-op + PV B-op
        bf16x8 bfr0[4], bfr1[4], btf[8];
#pragma unroll
        for (int k = 0; k < 4; ++k) {
            bfr0[k] = *reinterpret_cast<const bf16x8*>(xb + (size_t)(g0 + r) * W_ + k * 32 + q * 8);
            bfr1[k] = *reinterpret_cast<const bf16x8*>(xb + (size_t)(g0 + 16 + r) * W_ + k * 32 + q * 8);
        }
#pragma unroll
        for (int nt2 = 0; nt2 < 8; ++nt2)
            btf[nt2] = *reinterpret_cast<const bf16x8*>(xt + (size_t)(nt2 * 16 + r) * H_ + g0 + q * 8);

        f32x4 sacc0 = {0.f, 0.f, 0.f, 0.f}, sacc1 = {0.f, 0.f, 0.f, 0.f};
#pragma unroll
        for (int k = 0; k < 4; ++k) {
            sacc0 = __builtin_amdgcn_mfma_f32_16x16x32_bf16(afr[k], bfr0[k], sacc0, 0, 0, 0);
            sacc1 = __builtin_amdgcn_mfma_f32_16x16x32_bf16(afr[k], bfr1[k], sacc1, 0, 0, 0);
        }
        float sg0 = sb[g0 + r], sg1 = sb[g0 + 16 + r];
#pragma unroll
        for (int reg = 0; reg < 4; ++reg) {
            int h = q * 4 + reg;
            {
                float t = A * sacc0[reg] + C * sg0;
                float e = exp2f(fmaf(t, c1[reg], c0[reg]));
                zacc[reg] += e;
                int g = r;
                int cc = (g >> 3) ^ ((h >> 1) & 3);
                pw[h * 32 + cc * 8 + (g & 7)] = __float2bfloat16(e);
            }
            {
                float t = A * sacc1[reg] + C * sg1;
                float e = exp2f(fmaf(t, c1[reg], c0[reg]));
                zacc[reg] += e;
                int g = 16 + r;
                int cc = (g >> 3) ^ ((h >> 1) & 3);
                pw[h * 32 + cc * 8 + (g & 7)] = __float2bfloat16(e);
            }
        }
        // A-operand of PV from LDS (per-wave buffer; compiler inserts lgkmcnt)
        int cA = q ^ ((r >> 1) & 3);
        bf16x8 pa = *reinterpret_cast<const bf16x8*>(
            reinterpret_cast<const char*>(pw) + r * 64 + cA * 16);
#pragma unroll
        for (int nt2 = 0; nt2 < 8; ++nt2)
            o[nt2] = __builtin_amdgcn_mfma_f32_16x16x32_bf16(pa, btf[nt2], o[nt2], 0, 0, 0);
    }

    // Z: reduce across the 16 r-lanes of each h-row
#pragma unroll
    for (int reg = 0; reg < 4; ++reg) {
#pragma unroll
        for (int m = 1; m < 16; m <<= 1) zacc[reg] += __shfl_xor(zacc[reg], m, 64);
    }

    float g_ = gamma[0];
    const float* xrow = x + (size_t)b * H_ * W_;
    float* orow = out + (size_t)b * H_ * W_;
#pragma unroll
    for (int reg = 0; reg < 4; ++reg) {
        float sc = g_ / zacc[reg];
        int h = h0 + q * 4 + reg;
#pragma unroll
        for (int nt2 = 0; nt2 < 8; ++nt2) {
            int w = nt2 * 16 + r;
            size_t idx = (size_t)h * W_ + w;
            orow[idx] = fmaf(sc, o[nt2][reg], xrow[idx]);
        }
    }
}

// ---------------------------------------------------------------------------
extern "C" void kernel_launch(void* const* d_in, const int* in_sizes, int n_in,
                              void* d_out, int out_size, void* d_ws, size_t ws_size,
                              hipStream_t stream) {
    const float* x     = (const float*)d_in[0];
    const float* w1    = (const float*)d_in[1];
    const float* b1    = (const float*)d_in[2];
    const float* w2    = (const float*)d_in[3];
    const float* b2    = (const float*)d_in[4];
    const float* gamma = (const float*)d_in[5];
    float* out = (float*)d_out;

    char* ws = (char*)d_ws;
    const size_t XB_BYTES = (size_t)B_ * H_ * W_ * 2;   // 8 MB
    __hip_bfloat16* Xb = (__hip_bfloat16*)ws;
    __hip_bfloat16* XT = (__hip_bfloat16*)(ws + XB_BYTES);
    float* s  = (float*)(ws + 2 * XB_BYTES);

    prep_rows<<<B_ * H_ / 4, 256, 0, stream>>>(x, Xb, s);
    prep_xt<<<B_ * 32 * 2, 256, 0, stream>>>(x, XT);
    fused_attn<<<B_ * H_ / 64, 256, 0, stream>>>(x, Xb, XT, s, w1, b1, w2, b2, gamma, out);
}

// Round 4
// 258.969 us; speedup vs baseline: 2.0025x; 1.7929x over previous
//
#include <hip/hip_runtime.h>
#include <hip/hip_bf16.h>

// Sizes fixed by the reference
#define B_ 16
#define H_ 2048
#define W_ 128

using f32x4  = __attribute__((ext_vector_type(4))) float;
using bf16x8 = __attribute__((ext_vector_type(8))) short;

// ---------------------------------------------------------------------------
// prep: one block per 64 h-rows of one batch. Produces:
//  Xbt[b][hb=h/16][k=0..3][r=0..15][q=0..3][8]  (S-GEMM fragment-major, so a
//      wave's fragment load is a contiguous 1KB)
//  XTt[b][gb=g/32][w=0..127][gg=0..31]          (PV B-operand tiles, ditto)
//  cs[b][g] = (sum_c b1_c w2_c) * sum_w x[b,g,w]
// ---------------------------------------------------------------------------
__global__ __launch_bounds__(256) void prep(const float* __restrict__ x,
                                            const float* __restrict__ b1,
                                            const float* __restrict__ w2,
                                            __hip_bfloat16* __restrict__ Xbt,
                                            __hip_bfloat16* __restrict__ XTt,
                                            float* __restrict__ cs) {
    __shared__ float xs[64][130];
    __shared__ float psum[64][4];
    int b  = blockIdx.x >> 5;
    int h0 = (blockIdx.x & 31) * 64;
    const float* xb = x + ((size_t)b * H_ + h0) * W_;
    int t = threadIdx.x;
    // load 64x128 f32 tile, coalesced
    {
        int col = (t & 31) * 4, r0 = t >> 5;
#pragma unroll
        for (int p = 0; p < 8; ++p) {
            int row = p * 8 + r0;
            float4 v = *reinterpret_cast<const float4*>(xb + (size_t)row * W_ + col);
            xs[row][col] = v.x; xs[row][col + 1] = v.y;
            xs[row][col + 2] = v.z; xs[row][col + 3] = v.w;
        }
    }
    __syncthreads();
    // row sums
    {
        int row = t >> 2, quad = t & 3;
        float sum = 0.f;
#pragma unroll
        for (int j = 0; j < 32; ++j) sum += xs[row][quad * 32 + j];
        psum[row][quad] = sum;
    }
    __syncthreads();
    if (t < 64) {
        float C = 0.f;
#pragma unroll
        for (int c = 0; c < 8; ++c) C += b1[c] * w2[c];
        float s = psum[t][0] + psum[t][1] + psum[t][2] + psum[t][3];
        cs[b * H_ + h0 + t] = C * s;
    }
    // Xbt fragments: chunk c = (((hbl*4 + k)*16 + r)*4 + q), 8 elems each
    {
        __hip_bfloat16* outb = Xbt + (size_t)b * H_ * W_ + (size_t)(h0 >> 4) * W_ * 16;
#pragma unroll
        for (int ccb = 0; ccb < 4; ++ccb) {
            int c = ccb * 256 + t;
            int q = c & 3, r = (c >> 2) & 15, k = (c >> 6) & 3, hbl = c >> 8;
            int row = hbl * 16 + r, col = k * 32 + q * 8;
            bf16x8 v;
#pragma unroll
            for (int j = 0; j < 8; ++j) {
                union { __hip_bfloat16 h; short s; } u;
                u.h = __float2bfloat16(xs[row][col + j]);
                v[j] = u.s;
            }
            *reinterpret_cast<bf16x8*>(outb + (size_t)c * 8) = v;
        }
    }
    // XTt tiles: this block covers gb = h0/32 and h0/32 + 1
    {
        __hip_bfloat16* outt = XTt + (size_t)b * H_ * W_ + (size_t)(h0 >> 5) * W_ * 32;
#pragma unroll
        for (int ccb = 0; ccb < 4; ++ccb) {
            int c = ccb * 256 + t;                       // 0..1023
            int gs = (c & 3) * 8, w = (c >> 2) & 127, tile = c >> 9;
            bf16x8 v;
#pragma unroll
            for (int j = 0; j < 8; ++j) {
                union { __hip_bfloat16 h; short s; } u;
                u.h = __float2bfloat16(xs[tile * 32 + gs + j][w]);
                v[j] = u.s;
            }
            *reinterpret_cast<bf16x8*>(outt + ((size_t)(tile * 128 + w) * 32 + gs)) = v;
        }
    }
}

// ---------------------------------------------------------------------------
// Fused: block = 64 h-rows (4 waves x 16), wave keeps A-fragment in regs.
// sweep1: row min/max of t = A*S + cs[g];  sweep2: exp2 + Z + O = P @ X.
// All global fragment loads contiguous-1KB; S-operands register-double-buffered.
// ---------------------------------------------------------------------------
__global__ __launch_bounds__(256, 2) void fused_attn(
    const float* __restrict__ x,
    const __hip_bfloat16* __restrict__ Xbt, const __hip_bfloat16* __restrict__ XTt,
    const float* __restrict__ cs,
    const float* __restrict__ w1, const float* __restrict__ w2,
    const float* __restrict__ gamma, float* __restrict__ out) {
    __shared__ __hip_bfloat16 pbuf[4][2][512];   // per-wave 16h x 32g, dbuf

    float A = 0.f;
#pragma unroll
    for (int c = 0; c < 8; ++c) A += w1[c] * w2[c];

    int wave = threadIdx.x >> 6, lane = threadIdx.x & 63;
    int q = lane >> 4, r = lane & 15;

    // XCD swizzle: XCD k gets a contiguous 64-block span = 2 batches
    int bid = blockIdx.x;
    int swz = (bid & 7) * 64 + (bid >> 3);
    int b  = swz >> 5;
    int hb = swz & 31;
    int h0 = hb * 64 + wave * 16;

    const __hip_bfloat16* xbt = Xbt + (size_t)b * H_ * W_;
    const __hip_bfloat16* xtt = XTt + (size_t)b * H_ * W_;
    const float* csb = cs + b * H_;

    // A-fragment (16h x 128k) in regs for the whole kernel
    bf16x8 afr[4];
#pragma unroll
    for (int k = 0; k < 4; ++k)
        afr[k] = *reinterpret_cast<const bf16x8*>(
            xbt + ((size_t)((h0 >> 4) * 4 + k) * 16 + r) * 32 + q * 8);

    auto load_bfr = [&](bf16x8 d0[4], bf16x8 d1[4], int g0_) {
        int gb_ = g0_ >> 4;
#pragma unroll
        for (int k = 0; k < 4; ++k) {
            d0[k] = *reinterpret_cast<const bf16x8*>(
                xbt + ((size_t)(gb_ * 4 + k) * 16 + r) * 32 + q * 8);
            d1[k] = *reinterpret_cast<const bf16x8*>(
                xbt + ((size_t)((gb_ + 1) * 4 + k) * 16 + r) * 32 + q * 8);
        }
    };

    // ---------------- sweep 1: per-row min / max ----------------
    float mnv[4], mxv[4];
#pragma unroll
    for (int i = 0; i < 4; ++i) { mnv[i] = 3.4e38f; mxv[i] = -3.4e38f; }

    auto sweep1_body = [&](const bf16x8 f0[4], const bf16x8 f1[4], int g0_) {
        f32x4 s0 = {0.f, 0.f, 0.f, 0.f}, s1 = {0.f, 0.f, 0.f, 0.f};
#pragma unroll
        for (int k = 0; k < 4; ++k) {
            s0 = __builtin_amdgcn_mfma_f32_16x16x32_bf16(afr[k], f0[k], s0, 0, 0, 0);
            s1 = __builtin_amdgcn_mfma_f32_16x16x32_bf16(afr[k], f1[k], s1, 0, 0, 0);
        }
        float sg0 = csb[g0_ + r], sg1 = csb[g0_ + 16 + r];
#pragma unroll
        for (int reg = 0; reg < 4; ++reg) {
            float t0 = fmaf(A, s0[reg], sg0);
            float t1 = fmaf(A, s1[reg], sg1);
            mnv[reg] = fminf(mnv[reg], fminf(t0, t1));
            mxv[reg] = fmaxf(mxv[reg], fmaxf(t0, t1));
        }
    };

    {
        bf16x8 pa0[4], pa1[4], pb0[4], pb1[4];
        load_bfr(pa0, pa1, 0);
        for (int g0 = 0; g0 < H_; g0 += 64) {
            load_bfr(pb0, pb1, g0 + 32);
            sweep1_body(pa0, pa1, g0);
            load_bfr(pa0, pa1, g0 + 64);   // tail overread lands in ws, unused
            sweep1_body(pb0, pb1, g0 + 32);
        }
    }
#pragma unroll
    for (int reg = 0; reg < 4; ++reg) {
#pragma unroll
        for (int m = 1; m < 16; m <<= 1) {
            mnv[reg] = fminf(mnv[reg], __shfl_xor(mnv[reg], m, 64));
            mxv[reg] = fmaxf(mxv[reg], __shfl_xor(mxv[reg], m, 64));
        }
    }
    const float LOG2E = 1.4426950408889634f;
    float c1[4], c0v[4];
#pragma unroll
    for (int reg = 0; reg < 4; ++reg) {
        float inv = LOG2E / (mxv[reg] - mnv[reg] + 1e-8f);
        c1[reg]  = inv;
        c0v[reg] = -mnv[reg] * inv;
    }

    // ---------------- sweep 2: exp + Z + O = P @ X ----------------
    f32x4 o[8];
#pragma unroll
    for (int i = 0; i < 8; ++i) o[i] = (f32x4){0.f, 0.f, 0.f, 0.f};
    float zacc[4] = {0.f, 0.f, 0.f, 0.f};

    auto sweep2_body = [&](const bf16x8 f0[4], const bf16x8 f1[4], int g0_) {
        bf16x8 btf[8];
#pragma unroll
        for (int nt2 = 0; nt2 < 8; ++nt2)
            btf[nt2] = *reinterpret_cast<const bf16x8*>(
                xtt + (size_t)((g0_ >> 5) * 128 + nt2 * 16 + r) * 32 + q * 8);
        f32x4 s0 = {0.f, 0.f, 0.f, 0.f}, s1 = {0.f, 0.f, 0.f, 0.f};
#pragma unroll
        for (int k = 0; k < 4; ++k) {
            s0 = __builtin_amdgcn_mfma_f32_16x16x32_bf16(afr[k], f0[k], s0, 0, 0, 0);
            s1 = __builtin_amdgcn_mfma_f32_16x16x32_bf16(afr[k], f1[k], s1, 0, 0, 0);
        }
        float sg0 = csb[g0_ + r], sg1 = csb[g0_ + 16 + r];
        __hip_bfloat16* pw = pbuf[wave][(g0_ >> 5) & 1];
#pragma unroll
        for (int reg = 0; reg < 4; ++reg) {
            int h = q * 4 + reg;
            {
                float t = fmaf(A, s0[reg], sg0);
                float e = exp2f(fmaf(t, c1[reg], c0v[reg]));
                zacc[reg] += e;
                int g = r;
                int cc = (g >> 3) ^ ((h >> 1) & 3);
                pw[h * 32 + cc * 8 + (g & 7)] = __float2bfloat16(e);
            }
            {
                float t = fmaf(A, s1[reg], sg1);
                float e = exp2f(fmaf(t, c1[reg], c0v[reg]));
                zacc[reg] += e;
                int g = 16 + r;
                int cc = (g >> 3) ^ ((h >> 1) & 3);
                pw[h * 32 + cc * 8 + (g & 7)] = __float2bfloat16(e);
            }
        }
        int cA = q ^ ((r >> 1) & 3);
        bf16x8 pa = *reinterpret_cast<const bf16x8*>(
            reinterpret_cast<const char*>(pw) + r * 64 + cA * 16);
#pragma unroll
        for (int nt2 = 0; nt2 < 8; ++nt2)
            o[nt2] = __builtin_amdgcn_mfma_f32_16x16x32_bf16(pa, btf[nt2], o[nt2], 0, 0, 0);
    };

    {
        bf16x8 pa0[4], pa1[4], pb0[4], pb1[4];
        load_bfr(pa0, pa1, 0);
        for (int g0 = 0; g0 < H_; g0 += 64) {
            load_bfr(pb0, pb1, g0 + 32);
            sweep2_body(pa0, pa1, g0);
            load_bfr(pa0, pa1, g0 + 64);   // tail overread lands in ws, unused
            sweep2_body(pb0, pb1, g0 + 32);
        }
    }

    // Z: reduce across the 16 r-lanes of each h-row
#pragma unroll
    for (int reg = 0; reg < 4; ++reg) {
#pragma unroll
        for (int m = 1; m < 16; m <<= 1) zacc[reg] += __shfl_xor(zacc[reg], m, 64);
    }

    float g_ = gamma[0];
    const float* xrow = x + (size_t)b * H_ * W_;
    float* orow = out + (size_t)b * H_ * W_;
#pragma unroll
    for (int reg = 0; reg < 4; ++reg) {
        float sc = g_ / zacc[reg];
        int h = h0 + q * 4 + reg;
#pragma unroll
        for (int nt2 = 0; nt2 < 8; ++nt2) {
            int w = nt2 * 16 + r;
            size_t idx = (size_t)h * W_ + w;
            orow[idx] = fmaf(sc, o[nt2][reg], xrow[idx]);
        }
    }
}

// ---------------------------------------------------------------------------
extern "C" void kernel_launch(void* const* d_in, const int* in_sizes, int n_in,
                              void* d_out, int out_size, void* d_ws, size_t ws_size,
                              hipStream_t stream) {
    const float* x     = (const float*)d_in[0];
    const float* w1    = (const float*)d_in[1];
    const float* b1    = (const float*)d_in[2];
    const float* w2    = (const float*)d_in[3];
    const float* b2    = (const float*)d_in[4];
    const float* gamma = (const float*)d_in[5];
    float* out = (float*)d_out;
    (void)b2;

    char* ws = (char*)d_ws;
    const size_t XB_BYTES = (size_t)B_ * H_ * W_ * 2;   // 8 MB
    __hip_bfloat16* Xbt = (__hip_bfloat16*)ws;
    __hip_bfloat16* XTt = (__hip_bfloat16*)(ws + XB_BYTES);
    float* cs = (float*)(ws + 2 * XB_BYTES);

    prep<<<B_ * 32, 256, 0, stream>>>(x, b1, w2, Xbt, XTt, cs);
    fused_attn<<<B_ * H_ / 64, 256, 0, stream>>>(x, Xbt, XTt, cs, w1, w2, gamma, out);
}

// Round 5
// 171.034 us; speedup vs baseline: 3.0321x; 1.5141x over previous
//
#include <hip/hip_runtime.h>
#include <hip/hip_bf16.h>

// Sizes fixed by the reference
#define B_ 16
#define H_ 2048
#define W_ 128

using f32x4  = __attribute__((ext_vector_type(4))) float;
using bf16x8 = __attribute__((ext_vector_type(8))) short;

// async global->LDS, 16B per lane. LDS dest is wave-uniform base + lane*16;
// global src is per-lane.
#define GLOAD_LDS16(g, l) __builtin_amdgcn_global_load_lds( \
    (const __attribute__((address_space(1))) unsigned int*)(g), \
    (__attribute__((address_space(3))) unsigned int*)(l), 16, 0, 0)

__device__ inline short bf16bits(float f) {
    union { __hip_bfloat16 h; short s; } u;
    u.h = __float2bfloat16(f);
    return u.s;
}

// ---------------------------------------------------------------------------
// prep: one block per 64 g-rows of one batch. Produces lane-linear tiled
// layouts so every fused-kernel LDS read is consecutive-lane-consecutive-16B:
//  Xbt[b]: for gb=g/16, k=w/32: 64 chunks (lane l=q*16+r) of 8 bf16:
//          content X[gb*16+r][k*32+q*8+j]      (chunk idx = (gb*4+k)*64 + l)
//  XTt[b]: for g64=g/64, kt, nt2: 64 chunks (lane l=q*16+r) of 8 bf16:
//          content X[g64*64+kt*32+q*8+j][nt2*16+r]
//  cs[b][g] = (sum_c b1_c w2_c) * sum_w x[b,g,w]
// ---------------------------------------------------------------------------
__global__ __launch_bounds__(256) void prep(const float* __restrict__ x,
                                            const float* __restrict__ b1,
                                            const float* __restrict__ w2,
                                            __hip_bfloat16* __restrict__ Xbt,
                                            __hip_bfloat16* __restrict__ XTt,
                                            float* __restrict__ cs) {
    __shared__ float xs[64][136];   // 136 pad: float4-aligned rows
    __shared__ float psum[64][4];
    int b  = blockIdx.x >> 5;
    int g0 = (blockIdx.x & 31) * 64;
    const float* xb = x + ((size_t)b * H_ + g0) * W_;
    int t = threadIdx.x;
    {
        int col = (t & 31) * 4, r0 = t >> 5;
#pragma unroll
        for (int p = 0; p < 8; ++p) {
            int row = p * 8 + r0;
            float4 v = *reinterpret_cast<const float4*>(xb + (size_t)row * W_ + col);
            *reinterpret_cast<float4*>(&xs[row][col]) = v;
        }
    }
    __syncthreads();
    {
        int row = t >> 2, quad = t & 3;
        float sum = 0.f;
#pragma unroll
        for (int j = 0; j < 32; ++j) sum += xs[row][quad * 32 + j];
        psum[row][quad] = sum;
    }
    __syncthreads();
    if (t < 64) {
        float C = 0.f;
#pragma unroll
        for (int c = 0; c < 8; ++c) C += b1[c] * w2[c];
        float s = psum[t][0] + psum[t][1] + psum[t][2] + psum[t][3];
        cs[b * H_ + g0 + t] = C * s;
    }
    // Xbt chunks: block-local c = (gbl*4+k)*64 + q*16 + r
    {
        __hip_bfloat16* outb = Xbt + (size_t)b * H_ * W_ + (size_t)g0 * W_;
#pragma unroll
        for (int it = 0; it < 4; ++it) {
            int c = it * 256 + t;
            int r = c & 15, q = (c >> 4) & 3, k = (c >> 6) & 3, gbl = c >> 8;
            const float* src = &xs[gbl * 16 + r][k * 32 + q * 8];
            float4 v0 = *reinterpret_cast<const float4*>(src);
            float4 v1 = *reinterpret_cast<const float4*>(src + 4);
            bf16x8 v;
            v[0] = bf16bits(v0.x); v[1] = bf16bits(v0.y);
            v[2] = bf16bits(v0.z); v[3] = bf16bits(v0.w);
            v[4] = bf16bits(v1.x); v[5] = bf16bits(v1.y);
            v[6] = bf16bits(v1.z); v[7] = bf16bits(v1.w);
            *reinterpret_cast<bf16x8*>(outb + (size_t)c * 8) = v;
        }
    }
    // XTt chunks: block-local c = (kt*8+nt2)*64 + q*16 + r  (block = 1 g64 tile)
    {
        __hip_bfloat16* outt = XTt + (size_t)b * H_ * W_ + (size_t)g0 * W_;
#pragma unroll
        for (int it = 0; it < 4; ++it) {
            int c = it * 256 + t;
            int r = c & 15, q = (c >> 4) & 3, nt2 = (c >> 6) & 7, kt = (c >> 9) & 1;
            bf16x8 v;
#pragma unroll
            for (int j = 0; j < 8; ++j)
                v[j] = bf16bits(xs[kt * 32 + q * 8 + j][nt2 * 16 + r]);
            *reinterpret_cast<bf16x8*>(outt + (size_t)c * 8) = v;
        }
    }
}

// ---------------------------------------------------------------------------
// Fused: block = 64 h-rows (4 waves x 16). B-operands staged once per block
// into double-buffered LDS via async global_load_lds (64-g tiles, 16KB each
// array); stage for tile t+1 issued at body start, drained by the end-of-body
// barrier, so HBM/L2 latency hides under the whole body.
//  sweep1: row min/max of t = A*S + cs[g]
//  sweep2: e = exp2((t-mn)*inv), Z += e, O += P @ X (P via per-wave LDS)
// ---------------------------------------------------------------------------
__global__ __launch_bounds__(256, 2) void fused_attn(
    const float* __restrict__ x,
    const __hip_bfloat16* __restrict__ Xbt, const __hip_bfloat16* __restrict__ XTt,
    const float* __restrict__ cs,
    const float* __restrict__ w1, const float* __restrict__ w2,
    const float* __restrict__ gamma, float* __restrict__ out) {
    __shared__ __align__(16) char stgA[2][16384];   // Xbt tile (64g x 128k bf16)
    __shared__ __align__(16) char stgV[2][16384];   // XTt tile (128w x 64g bf16)
    __shared__ __align__(16) char pb[4][2048];      // per-wave P: 16h x 64g bf16

    float A = 0.f;
#pragma unroll
    for (int c = 0; c < 8; ++c) A += w1[c] * w2[c];

    int wave = threadIdx.x >> 6, lane = threadIdx.x & 63;
    int q = lane >> 4, r = lane & 15;

    // XCD swizzle: XCD k gets a contiguous 64-block span = 2 batches
    int bid = blockIdx.x;
    int swz = (bid & 7) * 64 + (bid >> 3);
    int b  = swz >> 5;
    int hb = swz & 31;
    int h0 = hb * 64 + wave * 16;

    const char* xbt = (const char*)(Xbt + (size_t)b * H_ * W_);
    const char* xtt = (const char*)(XTt + (size_t)b * H_ * W_);
    const float* csb = cs + b * H_;

    // A-fragment (16h x 128k) in regs for the whole kernel
    bf16x8 afr[4];
#pragma unroll
    for (int k = 0; k < 4; ++k)
        afr[k] = *reinterpret_cast<const bf16x8*>(
            xbt + (((size_t)(h0 >> 4) * 4 + k) * 64 + lane) * 16);

    // ---------------- sweep 1: per-row min / max ----------------
    float mnv[4], mxv[4];
#pragma unroll
    for (int i = 0; i < 4; ++i) { mnv[i] = 3.4e38f; mxv[i] = -3.4e38f; }

    {   // prologue: stage tile 0 (A only)
        const char* ga = xbt + wave * 4096 + lane * 16;
        char* la = stgA[0] + wave * 4096;
#pragma unroll
        for (int i = 0; i < 4; ++i) GLOAD_LDS16(ga + i * 1024, la + i * 1024);
    }
    __syncthreads();
    for (int t = 0; t < 32; ++t) {
        int cur = t & 1;
        if (t < 31) {
            const char* ga = xbt + (size_t)(t + 1) * 16384 + wave * 4096 + lane * 16;
            char* la = stgA[cur ^ 1] + wave * 4096;
#pragma unroll
            for (int i = 0; i < 4; ++i) GLOAD_LDS16(ga + i * 1024, la + i * 1024);
        }
        const char* sa = stgA[cur] + lane * 16;
#pragma unroll
        for (int gbl = 0; gbl < 4; ++gbl) {
            f32x4 acc = {0.f, 0.f, 0.f, 0.f};
#pragma unroll
            for (int k = 0; k < 4; ++k) {
                bf16x8 bfr = *reinterpret_cast<const bf16x8*>(sa + ((gbl * 4 + k) * 64) * 16);
                acc = __builtin_amdgcn_mfma_f32_16x16x32_bf16(afr[k], bfr, acc, 0, 0, 0);
            }
            float sg = csb[t * 64 + gbl * 16 + r];
#pragma unroll
            for (int reg = 0; reg < 4; ++reg) {
                float tv = fmaf(A, acc[reg], sg);
                mnv[reg] = fminf(mnv[reg], tv);
                mxv[reg] = fmaxf(mxv[reg], tv);
            }
        }
        __syncthreads();
    }
#pragma unroll
    for (int reg = 0; reg < 4; ++reg) {
#pragma unroll
        for (int m = 1; m < 16; m <<= 1) {
            mnv[reg] = fminf(mnv[reg], __shfl_xor(mnv[reg], m, 64));
            mxv[reg] = fmaxf(mxv[reg], __shfl_xor(mxv[reg], m, 64));
        }
    }
    const float LOG2E = 1.4426950408889634f;
    float c1[4], c0v[4];
#pragma unroll
    for (int reg = 0; reg < 4; ++reg) {
        float inv = LOG2E / (mxv[reg] - mnv[reg] + 1e-8f);
        c1[reg]  = inv;
        c0v[reg] = -mnv[reg] * inv;
    }

    // ---------------- sweep 2: exp + Z + O = P @ X ----------------
    f32x4 o[8];
#pragma unroll
    for (int i = 0; i < 8; ++i) o[i] = (f32x4){0.f, 0.f, 0.f, 0.f};
    float zacc[4] = {0.f, 0.f, 0.f, 0.f};

    {   // prologue: stage tile 0 (A + V)
        const char* ga = xbt + wave * 4096 + lane * 16;
        char* la = stgA[0] + wave * 4096;
        const char* gv = xtt + wave * 4096 + lane * 16;
        char* lv = stgV[0] + wave * 4096;
#pragma unroll
        for (int i = 0; i < 4; ++i) {
            GLOAD_LDS16(ga + i * 1024, la + i * 1024);
            GLOAD_LDS16(gv + i * 1024, lv + i * 1024);
        }
    }
    __syncthreads();
    char* pw = pb[wave];
    for (int t = 0; t < 32; ++t) {
        int cur = t & 1;
        if (t < 31) {
            const char* ga = xbt + (size_t)(t + 1) * 16384 + wave * 4096 + lane * 16;
            char* la = stgA[cur ^ 1] + wave * 4096;
            const char* gv = xtt + (size_t)(t + 1) * 16384 + wave * 4096 + lane * 16;
            char* lv = stgV[cur ^ 1] + wave * 4096;
#pragma unroll
            for (int i = 0; i < 4; ++i) {
                GLOAD_LDS16(ga + i * 1024, la + i * 1024);
                GLOAD_LDS16(gv + i * 1024, lv + i * 1024);
            }
        }
        const char* sa = stgA[cur] + lane * 16;
        const char* sv = stgV[cur] + lane * 16;
#pragma unroll
        for (int gbl = 0; gbl < 4; ++gbl) {
            f32x4 acc = {0.f, 0.f, 0.f, 0.f};
#pragma unroll
            for (int k = 0; k < 4; ++k) {
                bf16x8 bfr = *reinterpret_cast<const bf16x8*>(sa + ((gbl * 4 + k) * 64) * 16);
                acc = __builtin_amdgcn_mfma_f32_16x16x32_bf16(afr[k], bfr, acc, 0, 0, 0);
            }
            float sg = csb[t * 64 + gbl * 16 + r];
            int kt = gbl >> 1;
            int qq = ((gbl & 1) << 1) | (r >> 3);
            int jb = (r & 7) * 2;
#pragma unroll
            for (int reg = 0; reg < 4; ++reg) {
                float tv = fmaf(A, acc[reg], sg);
                float e = exp2f(fmaf(tv, c1[reg], c0v[reg]));
                zacc[reg] += e;
                int h = q * 4 + reg;
                *reinterpret_cast<short*>(pw + (kt * 64 + qq * 16 + h) * 16 + jb) = bf16bits(e);
            }
        }
        // PV: A-operand from per-wave pb (lane-linear), B from staged V tile
#pragma unroll
        for (int kt = 0; kt < 2; ++kt) {
            bf16x8 pa = *reinterpret_cast<const bf16x8*>(pw + kt * 1024 + lane * 16);
#pragma unroll
            for (int nt2 = 0; nt2 < 8; ++nt2) {
                bf16x8 btf = *reinterpret_cast<const bf16x8*>(sv + ((kt * 8 + nt2) * 64) * 16);
                o[nt2] = __builtin_amdgcn_mfma_f32_16x16x32_bf16(pa, btf, o[nt2], 0, 0, 0);
            }
        }
        __syncthreads();
    }

    // Z: reduce across the 16 r-lanes of each h-row
#pragma unroll
    for (int reg = 0; reg < 4; ++reg) {
#pragma unroll
        for (int m = 1; m < 16; m <<= 1) zacc[reg] += __shfl_xor(zacc[reg], m, 64);
    }

    float g_ = gamma[0];
    const float* xrow = x + (size_t)b * H_ * W_;
    float* orow = out + (size_t)b * H_ * W_;
#pragma unroll
    for (int reg = 0; reg < 4; ++reg) {
        float sc = g_ / zacc[reg];
        int h = h0 + q * 4 + reg;
#pragma unroll
        for (int nt2 = 0; nt2 < 8; ++nt2) {
            int w = nt2 * 16 + r;
            size_t idx = (size_t)h * W_ + w;
            orow[idx] = fmaf(sc, o[nt2][reg], xrow[idx]);
        }
    }
}

// ---------------------------------------------------------------------------
extern "C" void kernel_launch(void* const* d_in, const int* in_sizes, int n_in,
                              void* d_out, int out_size, void* d_ws, size_t ws_size,
                              hipStream_t stream) {
    const float* x     = (const float*)d_in[0];
    const float* w1    = (const float*)d_in[1];
    const float* b1    = (const float*)d_in[2];
    const float* w2    = (const float*)d_in[3];
    const float* b2    = (const float*)d_in[4];
    const float* gamma = (const float*)d_in[5];
    float* out = (float*)d_out;
    (void)b2;

    char* ws = (char*)d_ws;
    const size_t XB_BYTES = (size_t)B_ * H_ * W_ * 2;   // 8 MB
    __hip_bfloat16* Xbt = (__hip_bfloat16*)ws;
    __hip_bfloat16* XTt = (__hip_bfloat16*)(ws + XB_BYTES);
    float* cs = (float*)(ws + 2 * XB_BYTES);

    prep<<<B_ * 32, 256, 0, stream>>>(x, b1, w2, Xbt, XTt, cs);
    fused_attn<<<B_ * H_ / 64, 256, 0, stream>>>(x, Xbt, XTt, cs, w1, w2, gamma, out);
}